// Round 1
// baseline (67.478 us; speedup 1.0000x reference)
//
#include <hip/hip_runtime.h>
#include <hip/hip_bf16.h>

#define BB     8
#define NEW_S  2048
#define RES_S  4096
#define HDIM   1024   // floats per row
#define H4     (HDIM / 4)   // 256 float4 per row

// ---------------------------------------------------------------------------
// Kernel A: per-batch scan of counts -> inverse map inv[b*RES_S + j] = token i
// One block per batch, 1024 threads, each thread owns 2 tokens.
// Pack (zero_count << 32) | sum into a u64 so a single additive scan gives
// both the cumsum and the "prefix contains a nonpositive count" break flag.
// ---------------------------------------------------------------------------
__global__ __launch_bounds__(1024) void build_inv_kernel(
    const int* __restrict__ counts, int* __restrict__ inv) {
    const int b = blockIdx.x;
    const int t = threadIdx.x;          // 0..1023
    int* invb = inv + b * RES_S;

    // init this batch's inverse map (exclusively owned by this block)
#pragma unroll
    for (int k = 0; k < RES_S / 1024; ++k) invb[t + k * 1024] = -1;
    __syncthreads();

    const int* cb = counts + b * NEW_S;
    const int c0 = cb[2 * t];
    const int c1 = cb[2 * t + 1];

    // pack: low 32 = clamped sum contribution, high 32 = nonpositive flag
    const unsigned long long e0 =
        (unsigned long long)(unsigned)(c0 > 0 ? c0 : 0) |
        ((unsigned long long)(c0 <= 0) << 32);
    const unsigned long long e1 =
        (unsigned long long)(unsigned)(c1 > 0 ? c1 : 0) |
        ((unsigned long long)(c1 <= 0) << 32);
    const unsigned long long p = e0 + e1;

    // wave-level inclusive scan (wave = 64 lanes on CDNA)
    const int lane = t & 63;
    const int wave = t >> 6;            // 0..15
    unsigned long long x = p;
#pragma unroll
    for (int d = 1; d < 64; d <<= 1) {
        unsigned long long y = __shfl_up(x, d, 64);
        if (lane >= d) x += y;
    }

    __shared__ unsigned long long wsum[16];
    if (lane == 63) wsum[wave] = x;
    __syncthreads();
    if (t == 0) {                        // serial exclusive scan of 16 wave totals
        unsigned long long acc = 0;
#pragma unroll
        for (int w = 0; w < 16; ++w) {
            unsigned long long v = wsum[w];
            wsum[w] = acc;
            acc += v;
        }
    }
    __syncthreads();

    const unsigned long long excl  = wsum[wave] + (x - p); // exclusive prefix of this thread
    const unsigned long long incl0 = excl + e0;            // inclusive at token 2t
    const unsigned long long incl1 = incl0 + e1;           // inclusive at token 2t+1

    if ((incl0 >> 32) == 0ULL) {         // no break up to and including token 2t
        const int idx = (int)(incl0 & 0xffffffffULL) - 1;
        if (idx >= 0 && idx < RES_S) invb[idx] = 2 * t;
    }
    if ((incl1 >> 32) == 0ULL) {
        const int idx = (int)(incl1 & 0xffffffffULL) - 1;
        if (idx >= 0 && idx < RES_S) invb[idx] = 2 * t + 1;
    }
}

// ---------------------------------------------------------------------------
// Kernel B: out[b,j,:] = residual[b,j,:] + (inv[b,j] >= 0 ? hidden[b,inv,:] : 0)
// One 256-thread block per output row; float4 per thread.
// ---------------------------------------------------------------------------
__global__ __launch_bounds__(256) void fanout_add_kernel(
    const float4* __restrict__ hidden,
    const float4* __restrict__ residual,
    const int* __restrict__ inv,
    float4* __restrict__ out) {
    const int row = blockIdx.x;          // 0 .. B*RES_S-1
    const int b   = row >> 12;           // row / RES_S
    const int t   = threadIdx.x;         // 0..255

    const int src = inv[row];
    const size_t off = (size_t)row * H4 + t;
    float4 r = residual[off];
    if (src >= 0) {
        const float4 hv = hidden[((size_t)b * NEW_S + src) * H4 + t];
        r.x += hv.x; r.y += hv.y; r.z += hv.z; r.w += hv.w;
    }
    out[off] = r;
}

extern "C" void kernel_launch(void* const* d_in, const int* in_sizes, int n_in,
                              void* d_out, int out_size, void* d_ws, size_t ws_size,
                              hipStream_t stream) {
    const float* hidden   = (const float*)d_in[0];
    // d_in[1] = attention_mask (unused by reference)
    const int*   counts   = (const int*)d_in[2];
    const float* residual = (const float*)d_in[3];
    // d_in[4] = residual_attention_mask (unused by reference)
    float* out = (float*)d_out;

    int* inv = (int*)d_ws;               // B*RES_S ints = 128 KiB

    build_inv_kernel<<<BB, 1024, 0, stream>>>(counts, inv);
    fanout_add_kernel<<<BB * RES_S, 256, 0, stream>>>(
        (const float4*)hidden, (const float4*)residual, inv, (float4*)out);
}

// Round 2
// 60.256 us; speedup vs baseline: 1.1199x; 1.1199x over previous
//
#include <hip/hip_runtime.h>
#include <hip/hip_bf16.h>

#define BB     8
#define NEW_S  2048
#define RES_S  4096
#define HDIM   1024          // floats per row
#define H4     (HDIM / 4)    // 256 float4 per row

#define TPB    256
#define NBLK   2048          // 8 blocks/CU * 256 CUs -> full occupancy
#define TOTAL  (BB * RES_S * H4)          // 8,388,608 float4
#define ITERS  (TOTAL / (NBLK * TPB))     // 16 (exact)

typedef float f4 __attribute__((ext_vector_type(4)));

// ---------------------------------------------------------------------------
// Kernel A: per-batch scan of counts -> inverse map inv[b*RES_S + j] = token i
// One block per batch, 1024 threads, each thread owns 2 tokens.
// Pack (zero_count << 32) | sum into a u64 so a single additive scan gives
// both the cumsum and the "prefix contains a nonpositive count" break flag.
// ---------------------------------------------------------------------------
__global__ __launch_bounds__(1024) void build_inv_kernel(
    const int* __restrict__ counts, int* __restrict__ inv) {
    const int b = blockIdx.x;
    const int t = threadIdx.x;          // 0..1023
    int* invb = inv + b * RES_S;

#pragma unroll
    for (int k = 0; k < RES_S / 1024; ++k) invb[t + k * 1024] = -1;
    __syncthreads();

    const int* cb = counts + b * NEW_S;
    const int c0 = cb[2 * t];
    const int c1 = cb[2 * t + 1];

    const unsigned long long e0 =
        (unsigned long long)(unsigned)(c0 > 0 ? c0 : 0) |
        ((unsigned long long)(c0 <= 0) << 32);
    const unsigned long long e1 =
        (unsigned long long)(unsigned)(c1 > 0 ? c1 : 0) |
        ((unsigned long long)(c1 <= 0) << 32);
    const unsigned long long p = e0 + e1;

    const int lane = t & 63;
    const int wave = t >> 6;            // 0..15
    unsigned long long x = p;
#pragma unroll
    for (int d = 1; d < 64; d <<= 1) {
        unsigned long long y = __shfl_up(x, d, 64);
        if (lane >= d) x += y;
    }

    __shared__ unsigned long long wsum[16];
    if (lane == 63) wsum[wave] = x;
    __syncthreads();
    if (t == 0) {
        unsigned long long acc = 0;
#pragma unroll
        for (int w = 0; w < 16; ++w) {
            unsigned long long v = wsum[w];
            wsum[w] = acc;
            acc += v;
        }
    }
    __syncthreads();

    const unsigned long long excl  = wsum[wave] + (x - p);
    const unsigned long long incl0 = excl + e0;
    const unsigned long long incl1 = incl0 + e1;

    if ((incl0 >> 32) == 0ULL) {
        const int idx = (int)(incl0 & 0xffffffffULL) - 1;
        if (idx >= 0 && idx < RES_S) invb[idx] = 2 * t;
    }
    if ((incl1 >> 32) == 0ULL) {
        const int idx = (int)(incl1 & 0xffffffffULL) - 1;
        if (idx >= 0 && idx < RES_S) invb[idx] = 2 * t + 1;
    }
}

// ---------------------------------------------------------------------------
// Kernel B: out[b,j,:] = residual[b,j,:] + (inv[b,j] >= 0 ? hidden[b,inv,:] : 0)
// Grid-stride, 16 float4 per thread, 4 independent chains in flight.
// Nontemporal stores: out is write-only; keep LLC for the read streams.
// ---------------------------------------------------------------------------
__global__ __launch_bounds__(256) void fanout_add_kernel(
    const f4* __restrict__ hidden,
    const f4* __restrict__ residual,
    const int* __restrict__ inv,
    f4* __restrict__ out) {
    const int tid = blockIdx.x * TPB + threadIdx.x;

#pragma unroll 4
    for (int k = 0; k < ITERS; ++k) {
        const int e   = tid + k * (NBLK * TPB);
        const int row = e >> 8;              // e / H4
        const int src = inv[row];
        f4 r = residual[e];
        if (src >= 0) {
            const int b = row >> 12;         // row / RES_S
            const f4 h = hidden[(size_t)((b << 11) + src) * H4 + (e & (H4 - 1))];
            r += h;
        }
        __builtin_nontemporal_store(r, &out[e]);
    }
}

extern "C" void kernel_launch(void* const* d_in, const int* in_sizes, int n_in,
                              void* d_out, int out_size, void* d_ws, size_t ws_size,
                              hipStream_t stream) {
    const float* hidden   = (const float*)d_in[0];
    // d_in[1] = attention_mask (unused by reference)
    const int*   counts   = (const int*)d_in[2];
    const float* residual = (const float*)d_in[3];
    // d_in[4] = residual_attention_mask (unused by reference)
    float* out = (float*)d_out;

    int* inv = (int*)d_ws;               // B*RES_S ints = 128 KiB

    build_inv_kernel<<<BB, 1024, 0, stream>>>(counts, inv);
    fanout_add_kernel<<<NBLK, TPB, 0, stream>>>(
        (const f4*)hidden, (const f4*)residual, inv, (f4*)out);
}